// Round 8
// baseline (124.401 us; speedup 1.0000x reference)
//
#include <hip/hip_runtime.h>
#include <cstdint>
#include <cstddef>

// Problem constants
#define B_DIM 4096   // batch (GEMM M)
#define S_DIM 2048   // states (GEMM N)
#define D_DIM 2496   // feature dim (GEMM K)
#define QSCALE 127.0f
#define QSCALE2 16129.0f   // 127^2
#define KC 39        // k-chunks of 64 bytes

// R14: R13 (123.1us, first real win: coalesced transpose-prep + slot-major
// conflict-free LDS + counted-vmcnt pipeline) extended minimally on the SAME
// proven structure. R11 counters said latency-bound (MfmaUtil 17%, both
// pipes low, occ 18%); R13 removed conflicts + drains; residual = load
// latency vs compute cover. Depth-2 gave ~2 compute phases (~500-700 cyc)
// of cover vs HBM ~900 cyc (m126) — cold A fetches straddle it.
// Change: 4-buffer ring, DEPTH-3 prefetch (vmcnt(8): tile t ready, tiles
// t+1/t+2 in flight). LDS 4x16KB = 64KB -> still 2 blocks/CU (m132
// precedent: 64KB static OK). Barrier count unchanged. + T5 setprio(1)
// around the MFMA cluster (role-split per step exists; null-at-worst m190).
#define BM 128
#define BN 128
#define BK 64
#define BUFB ((BM + BN) * BK) // 16384 B per buffer (A 8 KB | B 8 KB)

typedef __attribute__((ext_vector_type(4))) int int4v;

// ---------------------------------------------------------------------------
// Prep (unchanged from R13, harness-verified): grid = 768 blocks =
// (256 A-rowblocks + 128 B-rowblocks) x 2 k-halves. Slot-major chunk:
// 16 rows x 64 k-bytes stored [slot4][row16][16B]; byte offset of
// (slot,row,f4) = 4*threadIdx; a linear 1KB copy (lane*16) IS the i8
// 16x16x64 fragment (m=lane&15, k16=lane>>4). Reads row-contiguous float4;
// writes u32 at chunkbase + 4t (block-contiguous 1KB). Partial norms to
// xsqp/msqp[half][row]; gemm epilogue sums the halves.
__global__ __launch_bounds__(256) void prep_kernel(
    const float* __restrict__ X, const float* __restrict__ Mx,
    unsigned char* __restrict__ Xq, unsigned char* __restrict__ Mq,
    float* __restrict__ xsqp, float* __restrict__ msqp)
{
    const int t    = threadIdx.x;
    const int bid  = blockIdx.x;
    const int rb   = bid >> 1;        // 0..383
    const int half = bid & 1;
    const int c0   = half ? 20 : 0;
    const int c1   = half ? KC : 20;

    const float* src; unsigned char* dst; float* part;
    if (rb < 256) {
        src  = X  + (size_t)(rb * 16) * D_DIM;
        dst  = Xq + (size_t)rb * (KC * 1024);
        part = xsqp + half * B_DIM + rb * 16;
    } else {
        const int r = rb - 256;
        src  = Mx + (size_t)(r * 16) * D_DIM;
        dst  = Mq + (size_t)r * (KC * 1024);
        part = msqp + half * S_DIM + r * 16;
    }

    const int slot = t >> 6;
    const int r16  = (t >> 2) & 15;
    const int f4   = t & 3;
    const float* srow = src + (size_t)r16 * D_DIM + slot * 16 + f4 * 4;

    float acc = 0.f;
    #pragma unroll 4
    for (int c = c0; c < c1; ++c) {
        const float4 v = *(const float4*)(srow + c * 64);
        acc += v.x * v.x + v.y * v.y + v.z * v.z + v.w * v.w;
        const unsigned int q0 = (unsigned char)__float2int_rn(v.x * QSCALE);
        const unsigned int q1 = (unsigned char)__float2int_rn(v.y * QSCALE);
        const unsigned int q2 = (unsigned char)__float2int_rn(v.z * QSCALE);
        const unsigned int q3 = (unsigned char)__float2int_rn(v.w * QSCALE);
        *(unsigned int*)(dst + (size_t)c * 1024 + t * 4) =
            q0 | (q1 << 8) | (q2 << 16) | (q3 << 24);
    }

    __shared__ float red[256];
    red[t] = acc;
    __syncthreads();
    if (t < 16) {
        float s = 0.f;
        #pragma unroll
        for (int s4 = 0; s4 < 4; ++s4)
            #pragma unroll
            for (int f = 0; f < 4; ++f)
                s += red[s4 * 64 + t * 4 + f];
        part[t] = s;
    }
}

// ---------------------------------------------------------------------------
// global -> LDS direct (async) load, 16 B per lane; contiguous 1KB per issue.
__device__ __forceinline__ void gld_lds16(const unsigned char* g, unsigned char* l) {
    __builtin_amdgcn_global_load_lds(
        (const __attribute__((address_space(1))) unsigned int*)g,
        (__attribute__((address_space(3))) unsigned int*)l,
        16, 0, 0);
}

// ---------------------------------------------------------------------------
__global__ __launch_bounds__(256) void gemm_kernel(
    const unsigned char* __restrict__ A,   // slot-major chunked [256 rb][39 kc][1024]
    const unsigned char* __restrict__ Bt,  // slot-major chunked [128 rb][39 kc][1024]
    const float* __restrict__ xsqp, const float* __restrict__ msqp,
    float* __restrict__ C)
{
    constexpr int N = S_DIM;

    __shared__ __align__(16) unsigned char lds[4 * BUFB];  // 64 KB, 4-buffer ring

    const int tid  = threadIdx.x;
    const int lane = tid & 63;
    const int wave = tid >> 6;       // 4 waves, 2x2 of 64x64
    const int wm = wave >> 1;
    const int wn = wave & 1;

    // B-panel-resident XCD mapping (R9): xcd = bid&7 round-robin (m09).
    //   bn = 2*xcd + (l&1)  -> B panel 0.64 MB, L2-resident all kernel.
    //   bm = l>>1           -> A-chunk shared by the adjacent l-pair only.
    const int bid = blockIdx.x;
    const int xcd = bid & 7;
    const int l   = bid >> 3;              // 0..63 within XCD
    const int bm  = l >> 1;                // 0..31
    const int bn  = xcd * 2 + (l & 1);     // 0..15

    // Staging: per K-step each wave copies 4 chunks (A rowblocks 2w,2w+1 and
    // B rowblocks 2w,2w+1), each a contiguous 1 KB at base + lane*16.
    const unsigned char* pA0 = A  + (size_t)((bm * 8 + 2 * wave    ) * KC) * 1024 + lane * 16;
    const unsigned char* pA1 = A  + (size_t)((bm * 8 + 2 * wave + 1) * KC) * 1024 + lane * 16;
    const unsigned char* pB0 = Bt + (size_t)((bn * 8 + 2 * wave    ) * KC) * 1024 + lane * 16;
    const unsigned char* pB1 = Bt + (size_t)((bn * 8 + 2 * wave + 1) * KC) * 1024 + lane * 16;
    const int dA0 = (2 * wave) * 1024;            // LDS offsets within buffer
    const int dA1 = dA0 + 1024;
    const int dB0 = 8192 + (2 * wave) * 1024;
    const int dB1 = dB0 + 1024;

    int4v acc[4][4] = {};

    // Fragment read offsets: linear lane*16 within each chunk (conflict-free).
    const int aoff = wm * 4096 + lane * 16;
    const int boff = 8192 + wn * 4096 + lane * 16;

#define STAGE(BUF) do { \
    gld_lds16(pA0, &lds[(BUF) + dA0]); \
    gld_lds16(pA1, &lds[(BUF) + dA1]); \
    gld_lds16(pB0, &lds[(BUF) + dB0]); \
    gld_lds16(pB1, &lds[(BUF) + dB1]); \
    pA0 += 1024; pA1 += 1024; pB0 += 1024; pB1 += 1024; \
} while (0)

#define COMPUTE(BUF) do { \
    int4v af[4], bf[4]; \
    _Pragma("unroll") \
    for (int i = 0; i < 4; ++i) { \
        af[i] = *(const int4v*)&lds[(BUF) + aoff + i * 1024]; \
        bf[i] = *(const int4v*)&lds[(BUF) + boff + i * 1024]; \
    } \
    __builtin_amdgcn_s_setprio(1); \
    _Pragma("unroll") \
    for (int mi = 0; mi < 4; ++mi) \
        _Pragma("unroll") \
        for (int ni = 0; ni < 4; ++ni) \
            acc[mi][ni] = __builtin_amdgcn_mfma_i32_16x16x64_i8( \
                af[mi], bf[ni], acc[mi][ni], 0, 0, 0); \
    __builtin_amdgcn_s_setprio(0); \
} while (0)

// Depth-3 steady state: at top of step t, outstanding = tiles t, t+1, t+2
// (4 loads each = 12). vmcnt(8) retires exactly tile t's 4. Barrier, then
// stage t+3 into the buffer consumed at t-1 (all waves passed that compute
// via this barrier), then compute tile t. Never drains below 8 in-loop.
#define STEP(CBUF, SBUF) do { \
    asm volatile("s_waitcnt vmcnt(8)" ::: "memory"); \
    __builtin_amdgcn_s_barrier(); \
    STAGE(SBUF); \
    COMPUTE(CBUF); \
} while (0)

    // Prologue: tiles 0,1,2 in flight (12 loads/wave).
    STAGE(0);
    STAGE(BUFB);
    STAGE(2 * BUFB);

    // Main loop: steps 0..35 (9 x 4, fully static buffer refs).
    // Step t: compute buf[t&3], stage tile t+3 into buf[(t+3)&3].
    for (int t = 0; t < 36; t += 4) {
        STEP(0,        3 * BUFB);
        STEP(BUFB,     0       );
        STEP(2 * BUFB, BUFB    );
        STEP(3 * BUFB, 2 * BUFB);
    }
    // Tails: t=36 (outstanding 36,37,38), t=37, t=38.
    asm volatile("s_waitcnt vmcnt(8)" ::: "memory");
    __builtin_amdgcn_s_barrier();
    COMPUTE(0);
    asm volatile("s_waitcnt vmcnt(4)" ::: "memory");
    __builtin_amdgcn_s_barrier();
    COMPUTE(BUFB);
    asm volatile("s_waitcnt vmcnt(0)" ::: "memory");
    __builtin_amdgcn_s_barrier();
    COMPUTE(2 * BUFB);

#undef STEP
#undef COMPUTE
#undef STAGE

    // Epilogue (verified mapping): col = lane&15, row = (lane>>4)*4 + reg.
    // Norms are two-part sums (prep halves). C = (2*cross/127^2 - xs - ms)/500.
    const int fr   = lane & 15;
    const int row0 = bm * BM + wm * 64 + (lane >> 4) * 4;
    const int col0 = bn * BN + wn * 64 + fr;
    float ms[4];
    #pragma unroll
    for (int ni = 0; ni < 4; ++ni)
        ms[ni] = msqp[col0 + ni * 16] + msqp[S_DIM + col0 + ni * 16];
    #pragma unroll
    for (int mi = 0; mi < 4; ++mi) {
        #pragma unroll
        for (int r = 0; r < 4; ++r) {
            const int row = row0 + mi * 16 + r;
            const float xs = xsqp[row] + xsqp[B_DIM + row];
            #pragma unroll
            for (int ni = 0; ni < 4; ++ni) {
                const float cr2 = (float)acc[mi][ni][r] * (2.0f / QSCALE2);
                const float v = (cr2 - xs - ms[ni]) * (1.0f / 500.0f);
                C[(size_t)row * N + col0 + ni * 16] = v;
            }
        }
    }
}

// ---------------------------------------------------------------------------
extern "C" void kernel_launch(void* const* d_in, const int* in_sizes, int n_in,
                              void* d_out, int out_size, void* d_ws, size_t ws_size,
                              hipStream_t stream) {
    const float* X  = (const float*)d_in[0];  // [4096, 2496]
    const float* Mx = (const float*)d_in[1];  // [2048, 2496]
    float* out = (float*)d_out;               // [4096, 2048]

    // Workspace (~15.4 MB): Xq slot-major | Mq slot-major | xsqp[2][4096] |
    // msqp[2][2048]
    unsigned char* Xq = (unsigned char*)d_ws;
    unsigned char* Mq = Xq + (size_t)256 * KC * 1024;
    float* xsqp = (float*)(Mq + (size_t)128 * KC * 1024);
    float* msqp = xsqp + 2 * B_DIM;

    prep_kernel<<<768, 256, 0, stream>>>(X, Mx, Xq, Mq, xsqp, msqp);

    dim3 grid(512);  // 32 bm x 16 bn via XCD-resident mapping, 2 blocks/CU
    gemm_kernel<<<grid, 256, 0, stream>>>(Xq, Mq, xsqp, msqp, out);
}

// Round 9
// 123.669 us; speedup vs baseline: 1.0059x; 1.0059x over previous
//
#include <hip/hip_runtime.h>
#include <cstdint>
#include <cstddef>

// Problem constants
#define B_DIM 4096   // batch (GEMM M)
#define S_DIM 2048   // states (GEMM N)
#define D_DIM 2496   // feature dim (GEMM K)
#define QSCALE 127.0f
#define QSCALE2 16129.0f   // 127^2
#define KC 39        // k-chunks of 64 bytes

// R15: REVERT to R13 (123.14us, session best). R14's depth-3 + setprio
// regressed to 124.4 (within the pre-committed null band): depth-2 already
// covers the L2-resident B / pair-warmed A latencies; depth-3 pays 64KB LDS
// + deeper prologue for nothing. Final configuration:
//  - prep: transpose prep — coalesced 64-B reads, contiguous 1KB slot-major
//    chunk writes, 2-part partial norms (summed in gemm epilogue).
//  - gemm: slot-major conflict-free LDS (fragment read = linear lane*16),
//    3-buffer counted vmcnt(4) pipeline (never drains in-loop),
//    B-panel-resident XCD mapping, 2 blocks/CU.
// Measured levers on this problem: conflict-free layout + counted pipeline
// + coalesced prep = -4.5us (R13); depth-3 null (R14); setprio null (R14);
// B LDS-bypass -5.6us regression (R10); no-LDS 1-wave -2.6us regression
// (R12); 2-phase@1blk/CU -5.3us regression (R7).
#define BM 128
#define BN 128
#define BK 64
#define BUFB ((BM + BN) * BK) // 16384 B per buffer (A 8 KB | B 8 KB)

typedef __attribute__((ext_vector_type(4))) int int4v;

// ---------------------------------------------------------------------------
// Prep: grid = 768 blocks = (256 A-rowblocks + 128 B-rowblocks) x 2 k-halves.
// Slot-major chunk (harness-verified): 16 rows x 64 k-bytes stored
// [slot4][row16][16B]; byte offset of (slot,row,f4) = 4*threadIdx; a linear
// 1KB copy (lane*16) IS the i8 16x16x64 fragment (m=lane&15, k16=lane>>4).
// Thread t: slot=t>>6, row=(t>>2)&15, f4=t&3. Reads row-contiguous float4;
// writes u32 at chunkbase + 4t (block-contiguous 1KB). Partial norms to
// xsqp/msqp[half][row]; gemm epilogue sums the halves.
__global__ __launch_bounds__(256) void prep_kernel(
    const float* __restrict__ X, const float* __restrict__ Mx,
    unsigned char* __restrict__ Xq, unsigned char* __restrict__ Mq,
    float* __restrict__ xsqp, float* __restrict__ msqp)
{
    const int t    = threadIdx.x;
    const int bid  = blockIdx.x;
    const int rb   = bid >> 1;        // 0..383
    const int half = bid & 1;
    const int c0   = half ? 20 : 0;
    const int c1   = half ? KC : 20;

    const float* src; unsigned char* dst; float* part;
    if (rb < 256) {
        src  = X  + (size_t)(rb * 16) * D_DIM;
        dst  = Xq + (size_t)rb * (KC * 1024);
        part = xsqp + half * B_DIM + rb * 16;
    } else {
        const int r = rb - 256;
        src  = Mx + (size_t)(r * 16) * D_DIM;
        dst  = Mq + (size_t)r * (KC * 1024);
        part = msqp + half * S_DIM + r * 16;
    }

    const int slot = t >> 6;
    const int r16  = (t >> 2) & 15;
    const int f4   = t & 3;
    const float* srow = src + (size_t)r16 * D_DIM + slot * 16 + f4 * 4;

    float acc = 0.f;
    #pragma unroll 4
    for (int c = c0; c < c1; ++c) {
        const float4 v = *(const float4*)(srow + c * 64);
        acc += v.x * v.x + v.y * v.y + v.z * v.z + v.w * v.w;
        const unsigned int q0 = (unsigned char)__float2int_rn(v.x * QSCALE);
        const unsigned int q1 = (unsigned char)__float2int_rn(v.y * QSCALE);
        const unsigned int q2 = (unsigned char)__float2int_rn(v.z * QSCALE);
        const unsigned int q3 = (unsigned char)__float2int_rn(v.w * QSCALE);
        *(unsigned int*)(dst + (size_t)c * 1024 + t * 4) =
            q0 | (q1 << 8) | (q2 << 16) | (q3 << 24);
    }

    __shared__ float red[256];
    red[t] = acc;
    __syncthreads();
    if (t < 16) {
        float s = 0.f;
        #pragma unroll
        for (int s4 = 0; s4 < 4; ++s4)
            #pragma unroll
            for (int f = 0; f < 4; ++f)
                s += red[s4 * 64 + t * 4 + f];
        part[t] = s;
    }
}

// ---------------------------------------------------------------------------
// global -> LDS direct (async) load, 16 B per lane; contiguous 1KB per issue.
__device__ __forceinline__ void gld_lds16(const unsigned char* g, unsigned char* l) {
    __builtin_amdgcn_global_load_lds(
        (const __attribute__((address_space(1))) unsigned int*)g,
        (__attribute__((address_space(3))) unsigned int*)l,
        16, 0, 0);
}

// ---------------------------------------------------------------------------
__global__ __launch_bounds__(256) void gemm_kernel(
    const unsigned char* __restrict__ A,   // slot-major chunked [256 rb][39 kc][1024]
    const unsigned char* __restrict__ Bt,  // slot-major chunked [128 rb][39 kc][1024]
    const float* __restrict__ xsqp, const float* __restrict__ msqp,
    float* __restrict__ C)
{
    constexpr int N = S_DIM;

    __shared__ __align__(16) unsigned char lds[3 * BUFB];  // 48 KB, 3 buffers

    const int tid  = threadIdx.x;
    const int lane = tid & 63;
    const int wave = tid >> 6;       // 4 waves, 2x2 of 64x64
    const int wm = wave >> 1;
    const int wn = wave & 1;

    // B-panel-resident XCD mapping (R9): xcd = bid&7 round-robin (m09).
    //   bn = 2*xcd + (l&1)  -> B panel 0.64 MB, L2-resident all kernel.
    //   bm = l>>1           -> A-chunk shared by the adjacent l-pair only.
    const int bid = blockIdx.x;
    const int xcd = bid & 7;
    const int l   = bid >> 3;              // 0..63 within XCD
    const int bm  = l >> 1;                // 0..31
    const int bn  = xcd * 2 + (l & 1);     // 0..15

    // Staging: per K-step each wave copies 4 chunks (A rowblocks 2w,2w+1 and
    // B rowblocks 2w,2w+1), each a contiguous 1 KB at base + lane*16.
    const unsigned char* pA0 = A  + (size_t)((bm * 8 + 2 * wave    ) * KC) * 1024 + lane * 16;
    const unsigned char* pA1 = A  + (size_t)((bm * 8 + 2 * wave + 1) * KC) * 1024 + lane * 16;
    const unsigned char* pB0 = Bt + (size_t)((bn * 8 + 2 * wave    ) * KC) * 1024 + lane * 16;
    const unsigned char* pB1 = Bt + (size_t)((bn * 8 + 2 * wave + 1) * KC) * 1024 + lane * 16;
    const int dA0 = (2 * wave) * 1024;            // LDS offsets within buffer
    const int dA1 = dA0 + 1024;
    const int dB0 = 8192 + (2 * wave) * 1024;
    const int dB1 = dB0 + 1024;

    int4v acc[4][4] = {};

    // Fragment read offsets: linear lane*16 within each chunk (conflict-free).
    const int aoff = wm * 4096 + lane * 16;
    const int boff = 8192 + wn * 4096 + lane * 16;

#define STAGE(BUF) do { \
    gld_lds16(pA0, &lds[(BUF) + dA0]); \
    gld_lds16(pA1, &lds[(BUF) + dA1]); \
    gld_lds16(pB0, &lds[(BUF) + dB0]); \
    gld_lds16(pB1, &lds[(BUF) + dB1]); \
    pA0 += 1024; pA1 += 1024; pB0 += 1024; pB1 += 1024; \
} while (0)

#define COMPUTE(BUF) do { \
    int4v af[4], bf[4]; \
    _Pragma("unroll") \
    for (int i = 0; i < 4; ++i) { \
        af[i] = *(const int4v*)&lds[(BUF) + aoff + i * 1024]; \
        bf[i] = *(const int4v*)&lds[(BUF) + boff + i * 1024]; \
    } \
    _Pragma("unroll") \
    for (int mi = 0; mi < 4; ++mi) \
        _Pragma("unroll") \
        for (int ni = 0; ni < 4; ++ni) \
            acc[mi][ni] = __builtin_amdgcn_mfma_i32_16x16x64_i8( \
                af[mi], bf[ni], acc[mi][ni], 0, 0, 0); \
} while (0)

// One step: wait own 4 loads for the tile about to be computed (4 newer stay
// in flight), publish via barrier, then stage tile t+2 into the buffer
// computed at t-1 (safe: all waves passed the barrier after computing it),
// then compute tile t. Never drains vmcnt to 0 in the main loop.
#define STEP(CBUF, SBUF) do { \
    asm volatile("s_waitcnt vmcnt(4)" ::: "memory"); \
    __builtin_amdgcn_s_barrier(); \
    STAGE(SBUF); \
    COMPUTE(CBUF); \
} while (0)

    // Prologue: tiles 0 and 1 in flight (8 loads/wave).
    STAGE(0);
    STAGE(BUFB);

    // Main loop: tiles 0..35 (12 x 3, fully static buffer refs), then 36.
    for (int t = 0; t < 36; t += 3) {
        STEP(0,        2 * BUFB);
        STEP(BUFB,     0       );
        STEP(2 * BUFB, BUFB    );
    }
    STEP(0, 2 * BUFB);   // t=36: stages tile 38 (last), computes tile 36

    // t=37: tile 38's 4 loads still in flight.
    asm volatile("s_waitcnt vmcnt(4)" ::: "memory");
    __builtin_amdgcn_s_barrier();
    COMPUTE(BUFB);
    // t=38: drain.
    asm volatile("s_waitcnt vmcnt(0)" ::: "memory");
    __builtin_amdgcn_s_barrier();
    COMPUTE(2 * BUFB);

#undef STEP
#undef COMPUTE
#undef STAGE

    // Epilogue (verified mapping): col = lane&15, row = (lane>>4)*4 + reg.
    // Norms are two-part sums (prep halves). C = (2*cross/127^2 - xs - ms)/500.
    const int fr   = lane & 15;
    const int row0 = bm * BM + wm * 64 + (lane >> 4) * 4;
    const int col0 = bn * BN + wn * 64 + fr;
    float ms[4];
    #pragma unroll
    for (int ni = 0; ni < 4; ++ni)
        ms[ni] = msqp[col0 + ni * 16] + msqp[S_DIM + col0 + ni * 16];
    #pragma unroll
    for (int mi = 0; mi < 4; ++mi) {
        #pragma unroll
        for (int r = 0; r < 4; ++r) {
            const int row = row0 + mi * 16 + r;
            const float xs = xsqp[row] + xsqp[B_DIM + row];
            #pragma unroll
            for (int ni = 0; ni < 4; ++ni) {
                const float cr2 = (float)acc[mi][ni][r] * (2.0f / QSCALE2);
                const float v = (cr2 - xs - ms[ni]) * (1.0f / 500.0f);
                C[(size_t)row * N + col0 + ni * 16] = v;
            }
        }
    }
}

// ---------------------------------------------------------------------------
extern "C" void kernel_launch(void* const* d_in, const int* in_sizes, int n_in,
                              void* d_out, int out_size, void* d_ws, size_t ws_size,
                              hipStream_t stream) {
    const float* X  = (const float*)d_in[0];  // [4096, 2496]
    const float* Mx = (const float*)d_in[1];  // [2048, 2496]
    float* out = (float*)d_out;               // [4096, 2048]

    // Workspace (~15.4 MB): Xq slot-major | Mq slot-major | xsqp[2][4096] |
    // msqp[2][2048]
    unsigned char* Xq = (unsigned char*)d_ws;
    unsigned char* Mq = Xq + (size_t)256 * KC * 1024;
    float* xsqp = (float*)(Mq + (size_t)128 * KC * 1024);
    float* msqp = xsqp + 2 * B_DIM;

    prep_kernel<<<768, 256, 0, stream>>>(X, Mx, Xq, Mq, xsqp, msqp);

    dim3 grid(512);  // 32 bm x 16 bn via XCD-resident mapping, 2 blocks/CU
    gemm_kernel<<<grid, 256, 0, stream>>>(Xq, Mq, xsqp, msqp, out);
}